// Round 6
// baseline (5489.007 us; speedup 1.0000x reference)
//
#include <hip/hip_runtime.h>
#include <cmath>

// ---------------------------------------------------------------------------
// 2-layer LSTM, T=256 B=64 D=H=1024. Launch-pipelined (round-5 resubmit; the
// round-5 bench failed on container acquisition, not kernel verification).
//
// Rounds 1-4 post-mortem: three different persistent-kernel signaling schemes
// (fences / replicated counters / per-producer flags) all cost 15-27 us/step
// -> the cross-block visibility path has a ~15us floor this model can't beat.
// The R0 launch path measured 5.3 us/step-equivalent. So: optimize launches.
//   - ONE fat step kernel per timestep runs L0 step s AND L1 step s-1
//     (512 blocks). All deps are cross-launch -> dispatch boundary = sync.
//   - L1's x-part folded into its K=2048 GEMM (no second xgemm pass, layers
//     overlap). L0's x-part stays in big chunked xgemms (parallel, efficient).
//   - 257 fat launches + ~2 xgemm chunks + 3 packs ~= 262 dispatches.
//
// Layouts (verified in R0 and rounds 1-4):
//  packed gate col p = h*4 + g   (g: 0=i,1=j,2=f,3=o ; orig col = g*1024+h)
//  A-pack (64 x K):  AP[mt][kt][lane][j] = A[mt*16 + (lane&15)][kt*32 + (lane>>4)*8 + j]
//  B-pack (K=2048 x G): WP[nt][kt<64][lane][j] = W[kt*32 + (lane>>4)*8 + j][origcol(nt*16 + (lane&15))]
//  MFMA 16x16x32 f16: D[row=(lane>>4)*4+r][col=lane&15]
// ---------------------------------------------------------------------------

typedef _Float16 half8 __attribute__((ext_vector_type(8)));
typedef float f32x4 __attribute__((ext_vector_type(4)));

constexpr int Tt = 256, Bb = 64, Gg = 4096;
constexpr size_t HPACK = 65536;            // halves per 64x1024 A-pack slab

__device__ __forceinline__ f32x4 zero4() { f32x4 z = {0.f, 0.f, 0.f, 0.f}; return z; }
__device__ __forceinline__ float sigmoidf_(float x) { return 1.f / (1.f + expf(-x)); }

// ---- pack W (fp32 [2048][4096]) -> full-K fp16 B-pack (verified r1-r4) -----
__global__ void pack_w_kernel(const float* __restrict__ W0, const float* __restrict__ W1,
                              _Float16* __restrict__ WP0, _Float16* __restrict__ WP1) {
    int idx = blockIdx.x * 256 + threadIdx.x;      // [0, 2^20)
    const float* src = blockIdx.y ? W1 : W0;
    _Float16* dst = blockIdx.y ? WP1 : WP0;
    int lane = idx & 63;
    int kt = (idx >> 6) & 63;
    int nt = idx >> 12;
    int p = nt * 16 + (lane & 15);
    int col = (p & 3) * 1024 + (p >> 2);
    int kbase = kt * 32 + (lane >> 4) * 8;
    half8 v;
#pragma unroll
    for (int j = 0; j < 8; ++j) v[j] = (_Float16)src[(size_t)(kbase + j) * Gg + col];
    *reinterpret_cast<half8*>(dst + (size_t)idx * 8) = v;
}

__global__ void pack_bias_kernel(const float* __restrict__ b0, const float* __restrict__ b1,
                                 float* __restrict__ bp0, float* __restrict__ bp1) {
    int idx = blockIdx.x * 256 + threadIdx.x;      // [0, 8192)
    int l = idx >> 12, p = idx & 4095;
    int col = (p & 3) * 1024 + (p >> 2);
    (l ? bp1 : bp0)[p] = (l ? b1 : b0)[col];
}

// ---- pack X: fp32 [16384][1024] -> fp16 A-pack (verified) ------------------
__global__ void pack_a_kernel(const float* __restrict__ X, _Float16* __restrict__ XP) {
    int idx = blockIdx.x * 256 + threadIdx.x;      // [0, 1024*32*64)
    int lane = idx & 63;
    int kt = (idx >> 6) & 31;
    int mt = idx >> 11;
    int m = mt * 16 + (lane & 15);
    int kbase = kt * 32 + (lane >> 4) * 8;
    const float* srow = X + (size_t)m * 1024 + kbase;
    half8 v;
#pragma unroll
    for (int j = 0; j < 8; ++j) v[j] = (_Float16)srow[j];
    *reinterpret_cast<half8*>(XP + (size_t)idx * 8) = v;
}

// ---- big x-part GEMM for layer 0: Z = XP@W0x + b0 (R0-verified structure) --
// block 256 = 4 waves (2x2), block tile 128x128, wave tile 64x64.
// B is the full-K pack; x-part = kt 0..31 (nt stride 64 kt).
__global__ __launch_bounds__(256) void xgemm_kernel(const _Float16* __restrict__ AP,
                                                    const _Float16* __restrict__ WP,
                                                    const float* __restrict__ bias,
                                                    float* __restrict__ Z) {
    int lane = threadIdx.x & 63, wave = threadIdx.x >> 6;
    int wrow = wave >> 1, wcol = wave & 1;
    int mtb = blockIdx.x * 8 + wrow * 4;
    int ntb = blockIdx.y * 8 + wcol * 4;

    f32x4 acc[4][4];
#pragma unroll
    for (int i = 0; i < 4; ++i)
#pragma unroll
        for (int j = 0; j < 4; ++j) acc[i][j] = zero4();

    for (int kt = 0; kt < 32; ++kt) {
        half8 a[4], b[4];
#pragma unroll
        for (int i = 0; i < 4; ++i)
            a[i] = *reinterpret_cast<const half8*>(AP + (((size_t)(mtb + i) * 32 + kt) * 64 + lane) * 8);
#pragma unroll
        for (int j = 0; j < 4; ++j)
            b[j] = *reinterpret_cast<const half8*>(WP + (((size_t)(ntb + j) * 64 + kt) * 64 + lane) * 8);
#pragma unroll
        for (int i = 0; i < 4; ++i)
#pragma unroll
            for (int j = 0; j < 4; ++j)
                acc[i][j] = __builtin_amdgcn_mfma_f32_16x16x32_f16(a[i], b[j], acc[i][j], 0, 0, 0);
    }

    int r0 = (lane >> 4) * 4, cc = lane & 15;
#pragma unroll
    for (int j = 0; j < 4; ++j) {
        int p = (ntb + j) * 16 + cc;
        float bs = bias[p];
#pragma unroll
        for (int i = 0; i < 4; ++i) {
            int mbase = (mtb + i) * 16 + r0;
#pragma unroll
            for (int r = 0; r < 4; ++r)
                Z[(size_t)(mbase + r) * Gg + p] = acc[i][j][r] + bs;
        }
    }
}

// ---- fused both-layer step kernel ------------------------------------------
// grid 512: blocks [0,256) = layer0 step s (needs s<Tt), blocks [256,512) =
// layer1 step s-1 (needs s>=1). 16 packed cols per block, 4 waves = 4 m-tiles.
__global__ __launch_bounds__(256) void lstm_step2_kernel(int s,
        const float* __restrict__ ZT,           // L0 x-part (+bias) for step s
        const _Float16* __restrict__ WP0,       // full-K packs
        const _Float16* __restrict__ WP1,
        const float* __restrict__ bp1,
        const _Float16* __restrict__ h1a,       // h1[s-1] A-pack (read)
        _Float16* __restrict__ h1b,             // h1[s]   A-pack (write)
        const _Float16* __restrict__ h2a,       // h2[s-2] A-pack (read)
        _Float16* __restrict__ h2b,             // h2[s-1] A-pack (write)
        float* __restrict__ c0, float* __restrict__ c1,
        float* __restrict__ out) {
    const int layer = blockIdx.x >> 8;
    const int nt = blockIdx.x & 255;
    const int lane = threadIdx.x & 63, w = threadIdx.x >> 6;
    __shared__ float zs[4][16][17];

    if (layer == 0) {
        if (s >= Tt) return;
        f32x4 acc = zero4();
        for (int kt = 0; kt < 32; ++kt) {
            half8 a = *reinterpret_cast<const half8*>(h1a + (((size_t)w * 32 + kt) * 64 + lane) * 8);
            half8 b = *reinterpret_cast<const half8*>(WP0 + (((size_t)nt * 64 + 32 + kt) * 64 + lane) * 8);
            acc = __builtin_amdgcn_mfma_f32_16x16x32_f16(a, b, acc, 0, 0, 0);
        }
        int q = lane >> 4, cc = lane & 15;
#pragma unroll
        for (int r = 0; r < 4; ++r)
            zs[w][q * 4 + r][cc] = acc[r] + ZT[(size_t)(w * 16 + q * 4 + r) * Gg + nt * 16 + cc];
        __syncthreads();

        int bl = lane >> 2, hl = lane & 3;
        float zi = zs[w][bl][hl * 4 + 0];
        float zj = zs[w][bl][hl * 4 + 1];
        float zf = zs[w][bl][hl * 4 + 2];
        float zo = zs[w][bl][hl * 4 + 3];
        int b = w * 16 + bl;
        int hcol = nt * 4 + hl;
        float cold = c0[(size_t)b * 1024 + hcol];
        float cn = cold * sigmoidf_(zf + 1.0f) + sigmoidf_(zi) * tanhf(zj);
        float hn = tanhf(cn) * sigmoidf_(zo);
        c0[(size_t)b * 1024 + hcol] = cn;
        h1b[(((size_t)w * 32 + (hcol >> 5)) * 64 + ((hcol >> 3) & 3) * 16 + bl) * 8 + (hcol & 7)] = (_Float16)hn;
    } else {
        if (s < 1) return;
        f32x4 acc = zero4();
        for (int kt = 0; kt < 32; ++kt) {     // h1[s-1] half (K rows 0..1023)
            half8 a = *reinterpret_cast<const half8*>(h1a + (((size_t)w * 32 + kt) * 64 + lane) * 8);
            half8 b = *reinterpret_cast<const half8*>(WP1 + (((size_t)nt * 64 + kt) * 64 + lane) * 8);
            acc = __builtin_amdgcn_mfma_f32_16x16x32_f16(a, b, acc, 0, 0, 0);
        }
        for (int kt = 0; kt < 32; ++kt) {     // h2[s-2] half (K rows 1024..2047)
            half8 a = *reinterpret_cast<const half8*>(h2a + (((size_t)w * 32 + kt) * 64 + lane) * 8);
            half8 b = *reinterpret_cast<const half8*>(WP1 + (((size_t)nt * 64 + 32 + kt) * 64 + lane) * 8);
            acc = __builtin_amdgcn_mfma_f32_16x16x32_f16(a, b, acc, 0, 0, 0);
        }
        int q = lane >> 4, cc = lane & 15;
        float bs = bp1[nt * 16 + cc];
#pragma unroll
        for (int r = 0; r < 4; ++r)
            zs[w][q * 4 + r][cc] = acc[r] + bs;
        __syncthreads();

        int bl = lane >> 2, hl = lane & 3;
        float zi = zs[w][bl][hl * 4 + 0];
        float zj = zs[w][bl][hl * 4 + 1];
        float zf = zs[w][bl][hl * 4 + 2];
        float zo = zs[w][bl][hl * 4 + 3];
        int b = w * 16 + bl;
        int hcol = nt * 4 + hl;
        float cold = c1[(size_t)b * 1024 + hcol];
        float cn = cold * sigmoidf_(zf + 1.0f) + sigmoidf_(zi) * tanhf(zj);
        float hn = tanhf(cn) * sigmoidf_(zo);
        c1[(size_t)b * 1024 + hcol] = cn;
        h2b[(((size_t)w * 32 + (hcol >> 5)) * 64 + ((hcol >> 3) & 3) * 16 + bl) * 8 + (hcol & 7)] = (_Float16)hn;
        out[(size_t)(s - 1) * 65536 + (size_t)b * 1024 + hcol] = hn;
    }
}

// ---------------------------------------------------------------------------
extern "C" void kernel_launch(void* const* d_in, const int* in_sizes, int n_in,
                              void* d_out, int out_size, void* d_ws, size_t ws_size,
                              hipStream_t stream) {
    const float* X  = (const float*)d_in[0];
    const float* W0 = (const float*)d_in[1];
    const float* b0 = (const float*)d_in[2];
    const float* W1 = (const float*)d_in[3];
    const float* b1 = (const float*)d_in[4];
    float* out = (float*)d_out;

    char* ws = (char*)d_ws;
    size_t off = 0;
    auto take = [&](size_t n) -> void* {
        void* r = ws + off;
        off += (n + 255) & ~(size_t)255;
        return r;
    };

    const size_t WPB = (size_t)2048 * Gg * 2;            // 16 MiB per packed W
    _Float16* WP0 = (_Float16*)take(WPB);
    _Float16* WP1 = (_Float16*)take(WPB);
    float* bp0 = (float*)take(Gg * 4);
    float* bp1 = (float*)take(Gg * 4);
    const size_t APB = (size_t)Tt * Bb * 1024 * 2;       // 32 MiB X A-pack
    _Float16* XP = (_Float16*)take(APB);
    _Float16* h1A = (_Float16*)take(2 * HPACK * 2);      // 256 KiB (2 parity slabs)
    _Float16* h2A = (_Float16*)take(2 * HPACK * 2);
    float* c0 = (float*)take((size_t)Bb * 1024 * 4);
    float* c1 = (float*)take((size_t)Bb * 1024 * 4);

    int Tc = 256;   // Z-chunk timesteps, shrink to fit workspace
    while (Tc > 8 && off + (size_t)Tc * Bb * Gg * 4 > ws_size) Tc >>= 1;
    float* Z = (float*)take((size_t)Tc * Bb * Gg * 4);

    hipMemsetAsync(h1A, 0, 2 * HPACK * 2, stream);
    hipMemsetAsync(h2A, 0, 2 * HPACK * 2, stream);
    hipMemsetAsync(c0, 0, (size_t)Bb * 1024 * 4, stream);
    hipMemsetAsync(c1, 0, (size_t)Bb * 1024 * 4, stream);

    pack_w_kernel<<<dim3(4096, 2), 256, 0, stream>>>(W0, W1, WP0, WP1);
    pack_bias_kernel<<<32, 256, 0, stream>>>(b0, b1, bp0, bp1);
    pack_a_kernel<<<8192, 256, 0, stream>>>(X, XP);

    auto launch_step = [&](int s, const float* ZT) {
        const _Float16* h1a = h1A + (size_t)((s + 1) & 1) * HPACK;   // h1[s-1]
        _Float16* h1b = h1A + (size_t)(s & 1) * HPACK;               // h1[s]
        const _Float16* h2a = h2A + (size_t)(s & 1) * HPACK;         // h2[s-2]
        _Float16* h2b = h2A + (size_t)((s + 1) & 1) * HPACK;         // h2[s-1]
        lstm_step2_kernel<<<512, 256, 0, stream>>>(s, ZT, WP0, WP1, bp1,
                                                   h1a, h1b, h2a, h2b, c0, c1, out);
    };

    for (int t0 = 0; t0 < Tt; t0 += Tc) {
        xgemm_kernel<<<dim3(Tc * Bb / 128, Gg / 128), 256, 0, stream>>>(
            XP + (size_t)t0 * HPACK, WP0, bp0, Z);
        for (int s = t0; s < t0 + Tc; ++s)
            launch_step(s, Z + (size_t)(s - t0) * Bb * Gg);
    }
    launch_step(Tt, Z);   // tail: layer-1 step 255 only (ZT unused)

    (void)in_sizes; (void)n_in; (void)out_size; (void)ws_size;
}